// Round 8
// baseline (257.970 us; speedup 1.0000x reference)
//
#include <hip/hip_runtime.h>
#include <math.h>

#define DIM 512
#define CD 14
#define NCODES 16384
#define NTOK 8192
#define EPS 1e-5f
#define LOG_EPS -11.5129254650f  // log(1e-5)
#define PTHRESH 1e-12f           // below this, p is invisible to f32 accumulation

// ws float layout:
//   [0 .. 16383]       avg_prob bins (atomic; zeroed inline by k_h blocks 0..1023)
//   [16384]            int ticket (zeroed by k_h block 0)
//   [16448 .. 18495]   per-block entropy partials (plain writes, every call)
//   [18496 .. 20543]   per-block commit partials
//   [24576 .. +NTOK*16) h[t][c] — numpy-f32-emulated projection, padded 16/token
#define WS_TICKET 16384
#define WS_ENT    16448
#define WS_COM    (16448 + 2048)
#define WS_H      24576
#define NBLK_H    1792            // NTOK*CD*4 threads / 256
#define NBLK_PS   (NTOK / 4)      // 2048 blocks, 4 tokens each
#define WT_S      513             // padded LDS row stride for transposed W_out

// Bit-exact emulation of numpy f32 einsum('bnd,cd->bnc'):
// sum_of_products_contig_contig_outstride0_two, BASELINE SIMD (SSE2/SSE3):
// 4 npyv lanes (no FMA: separate mul+add), 16-elem blocks, sub-block chain
// order 3,2,1,0, reduce (l0+l1)+(l2+l3) via hadd, then one f32 add of b_in[c].
// VALIDATED rounds 3-7. DO NOT change the arithmetic.
__global__ __launch_bounds__(256) void k_h(
    const float* __restrict__ x, const float* __restrict__ W_in,
    const float* __restrict__ b_in, float* __restrict__ ws)
{
#pragma clang fp contract(off)
    const int tid = threadIdx.x;
    // inline zeroing of bins + ticket (replaces memset/tail blocks; k_ps launch
    // is stream-ordered after k_h, so zeroing is complete before any atomic)
    if (blockIdx.x < 1024 && tid < 16) ws[blockIdx.x * 16 + tid] = 0.f;
    if (blockIdx.x == 0 && tid == 16) ((int*)ws)[WS_TICKET] = 0;

    const int gid = blockIdx.x * 256 + tid;
    const int dot = gid >> 2;       // t*CD + c
    const int j   = gid & 3;        // SSE lane
    const int t = dot / CD;
    const int c = dot - t * CD;
    const float* xp = x + (size_t)t * DIM + j;
    const float* wp = W_in + (size_t)c * DIM + j;

    float a = 0.f;
    #pragma unroll 4
    for (int i = 0; i < 32; ++i) {
        const int base = i * 16;
        const float x3 = xp[base + 12], w3 = wp[base + 12];
        const float x2 = xp[base + 8],  w2 = wp[base + 8];
        const float x1 = xp[base + 4],  w1 = wp[base + 4];
        const float x0 = xp[base + 0],  w0 = wp[base + 0];
        a = (x3 * w3) + a;   // s=3 sub-block first (npy chain order)
        a = (x2 * w2) + a;
        a = (x1 * w1) + a;
        a = (x0 * w0) + a;
    }
    // hadd pairing: (a0+a1) + (a2+a3)
    const float s2  = a + __shfl_xor(a, 1);
    const float sum = s2 + __shfl_xor(s2, 2);
    if (j == 0) ws[WS_H + (size_t)t * 16 + c] = sum + b_in[c];
}

// Merged project_out + sparse clipped-softmax stats + last-block finalize.
// One wave per token; W_out staged transposed in LDS (conflict-free column
// reads); subset enumeration parallel across 64 lanes.
__global__ __launch_bounds__(256) void k_ps(
    const float* __restrict__ hbuf, const float* __restrict__ W_out,
    const float* __restrict__ b_out, float* __restrict__ out,
    float* __restrict__ idx_out, float* __restrict__ ws,
    float* __restrict__ aux_out)
{
    __shared__ float wT[CD * WT_S];
    __shared__ float h_lds[4][16];
    __shared__ float f_lds[4][16];
    __shared__ float entred[4], comred[4];
    __shared__ int isLast;

    const int tid  = threadIdx.x;
    const int wave = tid >> 6, lane = tid & 63;
    const int tok  = blockIdx.x * 4 + wave;

    // Stage W_out[512][14] -> wT[c][d] (transposed, padded). Coalesced float4 reads.
    #pragma unroll
    for (int i = 0; i < 7; ++i) {
        const int e = (i * 256 + tid) * 4;
        const float4 v = *(const float4*)(W_out + e);
        {const int idx = e + 0; const int d = idx / CD; wT[(idx - d * CD) * WT_S + d] = v.x;}
        {const int idx = e + 1; const int d = idx / CD; wT[(idx - d * CD) * WT_S + d] = v.y;}
        {const int idx = e + 2; const int d = idx / CD; wT[(idx - d * CD) * WT_S + d] = v.z;}
        {const int idx = e + 3; const int d = idx / CD; wT[(idx - d * CD) * WT_S + d] = v.w;}
    }
    if (lane < CD) {
        const float hv = hbuf[(size_t)tok * 16 + lane];
        h_lds[wave][lane] = hv;
        f_lds[wave][lane] = __expf(-400.f * fabsf(hv));
    }
    __syncthreads();

    // signs + jstar (wave-uniform; static unroll -> registers)
    float s[CD];
    int jstar = 0;
    #pragma unroll
    for (int c = 0; c < CD; ++c) {
        const bool pos = h_lds[wave][c] > 0.f;
        s[c] = pos ? 1.f : -1.f;
        jstar |= (pos ? 1 : 0) << (13 - c);
    }
    if (lane == 0) idx_out[tok] = (float)jstar;

    // out = s @ W_out^T + b_out; conflict-free LDS column reads
    #pragma unroll
    for (int r = 0; r < 8; ++r) {
        const int d = r * 64 + lane;
        float v = b_out[d];
        #pragma unroll
        for (int c = 0; c < CD; ++c) v = fmaf(s[c], wT[c * WT_S + d], v);
        out[(size_t)tok * DIM + d] = v;
    }

    // sparse clipped-softmax: p = (prod over flipped hot bits of f)/Z
    // identity: sum_j p*log(clip(p,eps)) = LOG_EPS + sum_enum p*(max(log p,LOG_EPS)-LOG_EPS)
    float Z = 1.f, commit = 0.f;
    int hot = 0;
    #pragma unroll
    for (int c = 0; c < CD; ++c) {
        const float fv = f_lds[wave][c];
        const float ah = fabsf(h_lds[wave][c]);
        const float dd = ah - 1.f;           // (h - sign(h))^2 == (|h|-1)^2
        commit = fmaf(dd, dd, commit);
        Z *= 1.f + fv;
        hot |= (fv >= PTHRESH ? 1 : 0) << c;
    }
    const float invZ = 1.f / Z;
    const int nmask = 1 << __popc(hot);

    float ent = 0.f;
    for (int base = 0; base < nmask; base += 64) {
        const int si = base + lane;           // subset index over hot bits
        float prod = 1.f;
        int flip = 0, pos = 0;
        #pragma unroll
        for (int c = 0; c < CD; ++c) {
            if ((hot >> c) & 1) {
                if ((si >> pos) & 1) {
                    prod *= f_lds[wave][c];
                    flip |= 1 << (13 - c);
                }
                ++pos;
            }
        }
        if (si < nmask) {
            const float p = prod * invZ;
            if (p >= PTHRESH) {
                ent = fmaf(p, fmaxf(__logf(p), LOG_EPS) - LOG_EPS, ent);
                atomicAdd(&ws[jstar ^ flip], p);
            }
        }
    }
    #pragma unroll
    for (int off = 32; off; off >>= 1) ent += __shfl_xor(ent, off);
    if (lane == 0) { entred[wave] = ent; comred[wave] = commit; }
    __syncthreads();
    if (tid == 0) {
        ws[WS_ENT + blockIdx.x] = (entred[0] + entred[1]) + (entred[2] + entred[3]);
        ws[WS_COM + blockIdx.x] = (comred[0] + comred[1]) + (comred[2] + comred[3]);
    }

    // ---- last-block finalize (replaces k_final kernel) ----
    __threadfence();   // partials + bin atomics globally visible before ticket
    if (tid == 0) {
        const int tk = __hip_atomic_fetch_add((int*)ws + WS_TICKET, 1,
                                              __ATOMIC_ACQ_REL, __HIP_MEMORY_SCOPE_AGENT);
        isLast = (tk == NBLK_PS - 1);
    }
    __syncthreads();
    if (!isLast) return;
    __threadfence();

    float* red = wT;   // reuse staging LDS for the reductions
    float acc = 0.f;
    #pragma unroll
    for (int k = 0; k < 64; ++k) {
        const float b = __hip_atomic_load(ws + tid + k * 256,
                                          __ATOMIC_RELAXED, __HIP_MEMORY_SCOPE_AGENT);
        const float ap = b * (1.f / 8192.f);
        acc = fmaf(ap, __logf(fmaxf(ap, EPS)), acc);
    }
    float entp = 0.f, comp = 0.f;
    #pragma unroll
    for (int k = 0; k < 8; ++k) {
        entp += __hip_atomic_load(ws + WS_ENT + tid + k * 256,
                                  __ATOMIC_RELAXED, __HIP_MEMORY_SCOPE_AGENT);
        comp += __hip_atomic_load(ws + WS_COM + tid + k * 256,
                                  __ATOMIC_RELAXED, __HIP_MEMORY_SCOPE_AGENT);
    }
    red[tid] = acc; red[256 + tid] = entp; red[512 + tid] = comp;
    __syncthreads();
    for (int st = 128; st > 0; st >>= 1) {
        if (tid < st) {
            red[tid]       += red[tid + st];
            red[256 + tid] += red[256 + tid + st];
            red[512 + tid] += red[512 + tid + st];
        }
        __syncthreads();
    }
    if (tid == 0) {
        const float cbH = -red[0];
        // mean_t sum_j p log(clip p) == red[256]/NTOK + LOG_EPS
        const float psH = -(red[256] * (1.f / 8192.f) + LOG_EPS);
        const float commitT = red[512] * (1.f / (8192.f * 14.f));
        aux_out[0] = (psH - cbH) * 0.1f + commitT * 0.25f;
    }
}

extern "C" void kernel_launch(void* const* d_in, const int* in_sizes, int n_in,
                              void* d_out, int out_size, void* d_ws, size_t ws_size,
                              hipStream_t stream) {
    const float* x     = (const float*)d_in[0];
    const float* W_in  = (const float*)d_in[1];
    const float* b_in  = (const float*)d_in[2];
    const float* W_out = (const float*)d_in[3];
    const float* b_out = (const float*)d_in[4];
    // d_in[5] (codebook) is implicit in the factorized math.

    float* out     = (float*)d_out;                 // [4*2048*512]
    float* idx_out = out + (size_t)NTOK * DIM;      // [8192] as float
    float* aux_out = idx_out + NTOK;                // [1]
    float* ws      = (float*)d_ws;

    hipLaunchKernelGGL(k_h, dim3(NBLK_H), dim3(256), 0, stream,
                       x, W_in, b_in, ws);
    hipLaunchKernelGGL(k_ps, dim3(NBLK_PS), dim3(256), 0, stream,
                       ws + WS_H, W_out, b_out, out, idx_out, ws, aux_out);
}

// Round 9
// 54.138 us; speedup vs baseline: 4.7650x; 4.7650x over previous
//
#include <hip/hip_runtime.h>
#include <math.h>

#define DIM 512
#define CD 14
#define NCODES 16384
#define NTOK 8192
#define EPS 1e-5f
#define LOG_EPS -11.5129254650f  // log(1e-5)
#define PTHRESH 1e-12f           // below this, p is invisible to f32 accumulation

// ws float layout:
//   [0 .. 16383]          avg_prob accumulators (atomic; zeroed by k_h tail blocks)
//   [16384 .. 18431]      per-block entropy partials (k_ps, plain writes)
//   [18432 .. 20479]      per-block commit partials  (k_ps, plain writes)
//   [20480 .. +NTOK*16)   h[t][c] — numpy-f32-emulated projection, padded to 16/token
#define WS_ENT 16384
#define WS_COM (16384 + 2048)
#define WS_H   (16384 + 4096)
#define NBLK_H 1792   // NTOK*CD*4 threads / 256
#define NBLK_Z 64     // 64*256 == NCODES zero slots
#define NBLK_PS (NTOK / 4)
#define WT_S 513      // padded LDS row stride for transposed W_out

// Bit-exact emulation of numpy f32 einsum('bnd,cd->bnc'):
// sum_of_products_contig_contig_outstride0_two, BASELINE SIMD (SSE2/SSE3):
// 4 npyv lanes (no FMA: separate mul+add), 16-elem blocks, sub-block order
// 3,2,1,0, reduce = (l0+l1)+(l2+l3) via hadd, then one f32 add of b_in[c].
// VALIDATED round 3; lane-split validated round 4. DO NOT change arithmetic.
__global__ __launch_bounds__(256) void k_h(
    const float* __restrict__ x, const float* __restrict__ W_in,
    const float* __restrict__ b_in, float* __restrict__ ws)
{
#pragma clang fp contract(off)
    const int tid = threadIdx.x;
    if (blockIdx.x >= NBLK_H) {  // tail blocks: zero avg_prob accumulators
        ws[(blockIdx.x - NBLK_H) * 256 + tid] = 0.f;
        return;
    }
    const int gid = blockIdx.x * 256 + tid;
    const int dot = gid >> 2;       // t*CD + c
    const int j   = gid & 3;        // SSE lane
    const int t = dot / CD;
    const int c = dot - t * CD;
    const float* xp = x + (size_t)t * DIM + j;
    const float* wp = W_in + (size_t)c * DIM + j;

    float a = 0.f;
    #pragma unroll 4
    for (int i = 0; i < 32; ++i) {
        const int base = i * 16;
        const float x3 = xp[base + 12], w3 = wp[base + 12];
        const float x2 = xp[base + 8],  w2 = wp[base + 8];
        const float x1 = xp[base + 4],  w1 = wp[base + 4];
        const float x0 = xp[base + 0],  w0 = wp[base + 0];
        a = (x3 * w3) + a;   // s=3 sub-block first (npy chain order)
        a = (x2 * w2) + a;
        a = (x1 * w1) + a;
        a = (x0 * w0) + a;
    }
    // hadd pairing: (a0+a1) + (a2+a3)
    const float s2  = a + __shfl_xor(a, 1);
    const float sum = s2 + __shfl_xor(s2, 2);
    if (j == 0) ws[WS_H + (size_t)t * 16 + c] = sum + b_in[c];
}

// Merged project_out + sparse clipped-softmax stats. One wave per token.
// W_out staged transposed in LDS (conflict-free column reads); h/f staged in
// per-wave LDS (no runtime-indexed register arrays -> no scratch); subset
// enumeration parallel across 64 lanes.
__global__ __launch_bounds__(256) void k_ps(
    const float* __restrict__ hbuf, const float* __restrict__ W_out,
    const float* __restrict__ b_out, float* __restrict__ out,
    float* __restrict__ idx_out, float* __restrict__ ws)
{
    __shared__ float wT[CD * WT_S];
    __shared__ float h_lds[4][16];
    __shared__ float f_lds[4][16];
    __shared__ float entred[4], comred[4];

    const int tid  = threadIdx.x;
    const int wave = tid >> 6, lane = tid & 63;
    const int tok  = blockIdx.x * 4 + wave;

    // Stage W_out[512][14] -> wT[c][d] (transposed, padded). Coalesced float4 reads.
    #pragma unroll
    for (int i = 0; i < 7; ++i) {
        const int e = (i * 256 + tid) * 4;
        const float4 v = *(const float4*)(W_out + e);
        {const int idx = e + 0; const int d = idx / CD; wT[(idx - d * CD) * WT_S + d] = v.x;}
        {const int idx = e + 1; const int d = idx / CD; wT[(idx - d * CD) * WT_S + d] = v.y;}
        {const int idx = e + 2; const int d = idx / CD; wT[(idx - d * CD) * WT_S + d] = v.z;}
        {const int idx = e + 3; const int d = idx / CD; wT[(idx - d * CD) * WT_S + d] = v.w;}
    }
    if (lane < CD) {
        const float hv = hbuf[(size_t)tok * 16 + lane];
        h_lds[wave][lane] = hv;
        f_lds[wave][lane] = __expf(-400.f * fabsf(hv));
    }
    __syncthreads();

    // signs + jstar (wave-uniform; static unroll -> registers)
    float s[CD];
    int jstar = 0;
    #pragma unroll
    for (int c = 0; c < CD; ++c) {
        const bool pos = h_lds[wave][c] > 0.f;
        s[c] = pos ? 1.f : -1.f;
        jstar |= (pos ? 1 : 0) << (13 - c);
    }
    if (lane == 0) idx_out[tok] = (float)jstar;

    // out = s @ W_out^T + b_out; conflict-free LDS column reads
    #pragma unroll
    for (int r = 0; r < 8; ++r) {
        const int d = r * 64 + lane;
        float v = b_out[d];
        #pragma unroll
        for (int c = 0; c < CD; ++c) v = fmaf(s[c], wT[c * WT_S + d], v);
        out[(size_t)tok * DIM + d] = v;
    }

    // sparse clipped-softmax: p = (prod over flipped hot bits of f)/Z
    float Z = 1.f, commit = 0.f;
    int hot = 0;
    #pragma unroll
    for (int c = 0; c < CD; ++c) {
        const float fv = f_lds[wave][c];
        const float ah = fabsf(h_lds[wave][c]);
        const float dd = ah - 1.f;           // (h - sign(h))^2 == (|h|-1)^2
        commit = fmaf(dd, dd, commit);
        Z *= 1.f + fv;
        hot |= (fv >= PTHRESH ? 1 : 0) << c;
    }
    const float invZ = 1.f / Z;
    const int nmask = 1 << __popc(hot);

    float ent = 0.f;
    for (int base = 0; base < nmask; base += 64) {
        const int si = base + lane;           // subset index over hot bits
        float prod = 1.f;
        int flip = 0, pos = 0;
        #pragma unroll
        for (int c = 0; c < CD; ++c) {
            if ((hot >> c) & 1) {
                if ((si >> pos) & 1) {
                    prod *= f_lds[wave][c];
                    flip |= 1 << (13 - c);
                }
                ++pos;
            }
        }
        if (si < nmask) {
            const float p = prod * invZ;
            if (p >= PTHRESH) {
                ent = fmaf(p, fmaxf(__logf(p), LOG_EPS) - LOG_EPS, ent);
                atomicAdd(&ws[jstar ^ flip], p);
            }
        }
    }
    #pragma unroll
    for (int off = 32; off; off >>= 1) ent += __shfl_xor(ent, off);
    if (lane == 0) { entred[wave] = ent; comred[wave] = commit; }
    __syncthreads();
    if (tid == 0) {
        ws[WS_ENT + blockIdx.x] = (entred[0] + entred[1]) + (entred[2] + entred[3]);
        ws[WS_COM + blockIdx.x] = (comred[0] + comred[1]) + (comred[2] + comred[3]);
    }
}

__global__ __launch_bounds__(1024) void k_final(
    const float* __restrict__ ws, float* __restrict__ aux_out)
{
    __shared__ float r1[1024], r2[1024], r3[1024];
    const int tid = threadIdx.x;
    float acc = 0.f;
    #pragma unroll
    for (int k = 0; k < 16; ++k) {
        const float ap = ws[tid + k * 1024] * (1.f / 8192.f);
        acc = fmaf(ap, __logf(fmaxf(ap, EPS)), acc);
    }
    float entp = ws[WS_ENT + tid] + ws[WS_ENT + tid + 1024];
    float comp = ws[WS_COM + tid] + ws[WS_COM + tid + 1024];
    r1[tid] = acc; r2[tid] = entp; r3[tid] = comp;
    __syncthreads();
    for (int s = 512; s > 0; s >>= 1) {
        if (tid < s) {
            r1[tid] += r1[tid + s];
            r2[tid] += r2[tid + s];
            r3[tid] += r3[tid + s];
        }
        __syncthreads();
    }
    if (tid == 0) {
        const float cbH = -r1[0];
        // mean_t sum_j p log(clip p) == r2/NTOK + LOG_EPS
        const float psH = -(r2[0] * (1.f / 8192.f) + LOG_EPS);
        const float commit = r3[0] * (1.f / (8192.f * 14.f));
        aux_out[0] = (psH - cbH) * 0.1f + commit * 0.25f;
    }
}

extern "C" void kernel_launch(void* const* d_in, const int* in_sizes, int n_in,
                              void* d_out, int out_size, void* d_ws, size_t ws_size,
                              hipStream_t stream) {
    const float* x     = (const float*)d_in[0];
    const float* W_in  = (const float*)d_in[1];
    const float* b_in  = (const float*)d_in[2];
    const float* W_out = (const float*)d_in[3];
    const float* b_out = (const float*)d_in[4];
    // d_in[5] (codebook) is implicit in the factorized math.

    float* out     = (float*)d_out;                 // [4*2048*512]
    float* idx_out = out + (size_t)NTOK * DIM;      // [8192] as float
    float* aux_out = idx_out + NTOK;                // [1]
    float* ws      = (float*)d_ws;

    hipLaunchKernelGGL(k_h, dim3(NBLK_H + NBLK_Z), dim3(256), 0, stream,
                       x, W_in, b_in, ws);
    hipLaunchKernelGGL(k_ps, dim3(NBLK_PS), dim3(256), 0, stream,
                       ws + WS_H, W_out, b_out, out, idx_out, ws);
    hipLaunchKernelGGL(k_final, dim3(1), dim3(1024), 0, stream, ws, aux_out);
}